// Round 13
// baseline (44.398 us; speedup 1.0000x reference)
//
#include <hip/hip_runtime.h>
#include <math.h>

#define CN 256
#define DN 512

typedef __attribute__((ext_vector_type(8))) short bf16x8;
typedef __attribute__((ext_vector_type(4))) short bf16x4;
typedef __attribute__((ext_vector_type(4))) float f32x4;

__device__ __forceinline__ short f2bf(float f) {
  unsigned u = __float_as_uint(f);
  u += 0x7fffu + ((u >> 16) & 1u);
  return (short)(u >> 16);
}

__device__ __forceinline__ bf16x8 pack8(float4 a, float4 b) {
  bf16x8 r;
  r[0] = f2bf(a.x); r[1] = f2bf(a.y); r[2] = f2bf(a.z); r[3] = f2bf(a.w);
  r[4] = f2bf(b.x); r[5] = f2bf(b.y); r[6] = f2bf(b.z); r[7] = f2bf(b.w);
  return r;
}

__device__ __forceinline__ float d4(float4 v) {
  return v.x * v.x + v.y * v.y + v.z * v.z + v.w * v.w;
}

struct Pk {
  const float *img_feature, *text, *img, *neg;
  const float *p_t, *aw_t, *ab_t, *p_i, *aw_i, *ab_i;
  const float *W_tt, *b_tt, *W_it, *b_it, *W_ntt, *b_ntt;
  float* out; float* ws;
};

// ---- f32 workspace (float offsets) ----
#define WF_S   0
#define WF_E   327680
#define WF_RP  524288
#define WF_EC  534528
#define WF_TW  540672
#define WF_BF  933888

// ---- bf16 panel region (short offsets) ----
#define SB_ETP   1703936
#define SB_PW    1966080

__device__ __forceinline__ void mfma_tiles(const short* at, const short* bt,
                                           int wr, int wc, int lane, f32x4 (&acc)[2][2]) {
  const bf16x8 fa0 = *(const bf16x8*)(at + ((wr << 1) << 9) + (lane << 3));
  const bf16x8 fa1 = *(const bf16x8*)(at + (((wr << 1) + 1) << 9) + (lane << 3));
  const bf16x8 fb0 = *(const bf16x8*)(bt + ((wc << 1) << 9) + (lane << 3));
  const bf16x8 fb1 = *(const bf16x8*)(bt + (((wc << 1) + 1) << 9) + (lane << 3));
  acc[0][0] = __builtin_amdgcn_mfma_f32_16x16x32_bf16(fa0, fb0, acc[0][0], 0, 0, 0);
  acc[0][1] = __builtin_amdgcn_mfma_f32_16x16x32_bf16(fa0, fb1, acc[0][1], 0, 0, 0);
  acc[1][0] = __builtin_amdgcn_mfma_f32_16x16x32_bf16(fa1, fb0, acc[1][0], 0, 0, 0);
  acc[1][1] = __builtin_amdgcn_mfma_f32_16x16x32_bf16(fa1, fb1, acc[1][1], 0, 0, 0);
}

// ---- S1: 8 NT GEMMs + 7 pre-GEMMs, pipelined staging, XCD-swizzled ----
__global__ __launch_bounds__(512) void s1_k(Pk p) {
  float* ws = p.ws;
  short* SH = (short*)(ws + WF_BF);
  __shared__ __align__(16) short As[8192];
  __shared__ __align__(16) short Bs[8192];
  __shared__ float accx[4][64][16];
  __shared__ float invA_lds[64], invB_lds[64];
  // XCD-aware bijective swizzle: 352 = 8 * 44 (consecutive logical tiles ->
  // same XCD -> shared operand panels stay L2-resident)
  const int bid = ((blockIdx.x & 7) * 44) + (blockIdx.x >> 3);
  const int tid = threadIdx.x;
  const int lane = tid & 63, w = tid >> 6;
  const int q = w & 3, kh = w >> 2;
  const int wr = q >> 1, wc = q & 1;
  const int sr = (tid & 255) >> 2, sq = tid & 3;

  const float* XL[7] = {p.text, p.img, p.neg, p.aw_t, p.aw_i, p.p_t, p.p_i};

  if (bid < 128) {
    const int job = bid >> 4, tile = bid & 15;
    const int bm = (tile >> 2) << 6, bn = (tile & 3) << 6;

    const int AM[8] = {0, 1, 0, 2, 0, 0, 1, 0};
    const int BM[8] = {0, 1, 1, 2, 2, 3, 4, 4};
    const float* A = XL[AM[job]];
    const float* B = XL[BM[job]];
    const float* srcT = (tid < 256 ? A + (size_t)(bm + sr) * 512
                                   : B + (size_t)(bn + sr) * 512) + (sq << 3);
    short* dst = (tid < 256) ? As : Bs;
    f32x4 acc[2][2] = {};
    float ss = 0.f;
    float4 r0[8];
#pragma unroll
    for (int ks = 0; ks < 4; ++ks) {
      r0[2 * ks]     = *(const float4*)(srcT + ks * 32);
      r0[2 * ks + 1] = *(const float4*)(srcT + ks * 32 + 4);
    }
    // out-init / passthrough issued AFTER chunk-0 loads (latency overlap)
    if (tid < 256) p.out[4 * CN * DN + bid * 256 + tid] = p.img_feature[bid * 256 + tid];
    {
      const int i0 = bid * 1024 + tid;
      p.out[i0] = 0.5f * p.text[i0];
      p.out[i0 + 512] = 0.5f * p.text[i0 + 512];
    }
    for (int ck = 0; ck < 4; ++ck) {
#pragma unroll
      for (int ks = 0; ks < 4; ++ks) {
        ss += d4(r0[2 * ks]) + d4(r0[2 * ks + 1]);
        *(bf16x8*)&dst[ks * 2048 + ((sr >> 4) << 9) + (sq << 7) + ((sr & 15) << 3)]
            = pack8(r0[2 * ks], r0[2 * ks + 1]);
      }
      __syncthreads();
      if (ck < 3) {
        const float* s2 = srcT + (ck + 1) * 128;
#pragma unroll
        for (int ks = 0; ks < 4; ++ks) {
          r0[2 * ks]     = *(const float4*)(s2 + ks * 32);
          r0[2 * ks + 1] = *(const float4*)(s2 + ks * 32 + 4);
        }
      }
#pragma unroll
      for (int t3 = kh * 2; t3 < kh * 2 + 2; ++t3)
        mfma_tiles(As + t3 * 2048, Bs + t3 * 2048, wr, wc, lane, acc);
      __syncthreads();
    }

    if (job < 5) {
      ss += __shfl_xor(ss, 1, 64);
      ss += __shfl_xor(ss, 2, 64);
      if (sq == 0) {
        const float iv = 1.f / fmaxf(sqrtf(ss), 1e-12f);
        if (tid < 256) invA_lds[sr] = iv;
        else           invB_lds[sr] = iv;
      }
    }
    if (kh) {
#pragma unroll
      for (int mi = 0; mi < 2; ++mi)
#pragma unroll
        for (int ni = 0; ni < 2; ++ni)
#pragma unroll
          for (int jx = 0; jx < 4; ++jx)
            accx[q][lane][(mi * 2 + ni) * 4 + jx] = acc[mi][ni][jx];
    }
    __syncthreads();
    if (kh) return;
#pragma unroll
    for (int mi = 0; mi < 2; ++mi)
#pragma unroll
      for (int ni = 0; ni < 2; ++ni)
#pragma unroll
        for (int jx = 0; jx < 4; ++jx)
          acc[mi][ni][jx] += accx[q][lane][(mi * 2 + ni) * 4 + jx];

    float sv[2][2][4];
    if (job < 5) {
      float* C = ws + WF_S + job * 65536;
#pragma unroll
      for (int mi = 0; mi < 2; ++mi)
#pragma unroll
        for (int ni = 0; ni < 2; ++ni) {
          const int cl = (wc << 5) + (ni << 4) + (lane & 15);
#pragma unroll
          for (int jx = 0; jx < 4; ++jx) {
            const int rl = (wr << 5) + (mi << 4) + ((lane >> 4) << 2) + jx;
            const float v = acc[mi][ni][jx] * invA_lds[rl] * invB_lds[cl];
            sv[mi][ni][jx] = v;
            C[(size_t)(bm + rl) * CN + bn + cl] = v;
          }
        }
      float* rp = ws + WF_RP + job * 2048 + ((bn >> 5) + wc) * 256;
#pragma unroll
      for (int mi = 0; mi < 2; ++mi)
#pragma unroll
        for (int jx = 0; jx < 4; ++jx) {
          float s = fmaxf(sv[mi][0][jx], 0.f) + fmaxf(sv[mi][1][jx], 0.f);
          s += __shfl_xor(s, 1, 64); s += __shfl_xor(s, 2, 64);
          s += __shfl_xor(s, 4, 64); s += __shfl_xor(s, 8, 64);
          if ((lane & 15) == 0) {
            const int rl = (wr << 5) + (mi << 4) + ((lane >> 4) << 2) + jx;
            rp[bm + rl] = s;
          }
        }
    } else {
      const int z = job - 5;
      const float* bias = (job == 5) ? p.ab_t : p.ab_i;
      float* C = ws + WF_E + z * 65536;
#pragma unroll
      for (int mi = 0; mi < 2; ++mi)
#pragma unroll
        for (int ni = 0; ni < 2; ++ni) {
          const int cl = (wc << 5) + (ni << 4) + (lane & 15);
          const int rb2 = (wr << 5) + (mi << 4) + ((lane >> 4) << 2);
#pragma unroll
          for (int jx = 0; jx < 4; ++jx) {
            const float v = expf(acc[mi][ni][jx] + bias[bn + cl]);
            sv[mi][ni][jx] = v;
            C[(size_t)(bm + rb2 + jx) * CN + bn + cl] = v;
          }
          if (z < 2) {
            bf16x4 pk;
#pragma unroll
            for (int jx = 0; jx < 4; ++jx) pk[jx] = f2bf(sv[mi][ni][jx]);
            short* ET = SH + SB_ETP + z * 65536 + (bn >> 6) * 16384 + (bm >> 5) * 2048;
            const int idx = (rb2 >> 5) * 2048 + ((cl >> 4) << 9) + (((rb2 & 31) >> 3) << 7)
                          + ((cl & 15) << 3) + (rb2 & 7);
            *(bf16x4*)(ET + idx) = pk;
          }
        }
      if (z < 2) {
        float* ec = ws + WF_EC + z * 2048 + ((bm >> 5) + wr) * 256;
#pragma unroll
        for (int ni = 0; ni < 2; ++ni) {
          float s = 0.f;
#pragma unroll
          for (int mi = 0; mi < 2; ++mi)
#pragma unroll
            for (int jx = 0; jx < 4; ++jx) s += sv[mi][ni][jx];
          s += __shfl_xor(s, 16, 64); s += __shfl_xor(s, 32, 64);
          if ((lane >> 4) == 0) ec[bn + (wc << 5) + (ni << 4) + (lane & 15)] = s;
        }
      }
    }
  } else {
    // pre-GEMMs: X@W, 64x64 tiles, pipelined
    const int t2 = bid - 128, job = t2 >> 5, tile = t2 & 31;
    const int bm = (tile >> 3) << 6, bn = (tile & 7) << 6;
    const int AJ[7] = {5, 0, 6, 1, 0, 2, 0};
    const int WJ[7] = {0, 0, 1, 1, 1, 2, 2};
    const int TP[7] = {0, 1, 2, 3, -1, 4, -1};
    const int F32[7] = {-1, 0, -1, -1, 1, -1, 2};
    const float* A = XL[AJ[job]];
    const float* W = (WJ[job] == 0) ? p.W_tt : (WJ[job] == 1) ? p.W_it : p.W_ntt;
    const int wv4 = w & 3;
    const int d = bn + lane;
    f32x4 acc[2][2] = {};
    const float* srcA = A + (size_t)(bm + sr) * 512 + (sq << 3);
    float4 ra[8];
    float wreg[32];
    if (tid < 256) {
#pragma unroll
      for (int ks = 0; ks < 4; ++ks) {
        ra[2 * ks]     = *(const float4*)(srcA + ks * 32);
        ra[2 * ks + 1] = *(const float4*)(srcA + ks * 32 + 4);
      }
    } else {
#pragma unroll
      for (int c = 0; c < 4; ++c) {
        const int m0 = wv4 * 32 + c * 8;
#pragma unroll
        for (int j = 0; j < 8; ++j) wreg[c * 8 + j] = W[(size_t)(m0 + j) * 512 + d];
      }
    }
    for (int ck = 0; ck < 4; ++ck) {
      if (tid < 256) {
#pragma unroll
        for (int ks = 0; ks < 4; ++ks)
          *(bf16x8*)&As[ks * 2048 + ((sr >> 4) << 9) + (sq << 7) + ((sr & 15) << 3)]
              = pack8(ra[2 * ks], ra[2 * ks + 1]);
      } else {
#pragma unroll
        for (int c = 0; c < 4; ++c) {
          bf16x8 pk;
#pragma unroll
          for (int j = 0; j < 8; ++j) pk[j] = f2bf(wreg[c * 8 + j]);
          *(bf16x8*)&Bs[wv4 * 2048 + ((lane >> 4) << 9) + (c << 7) + ((lane & 15) << 3)] = pk;
        }
      }
      __syncthreads();
      if (ck < 3) {
        if (tid < 256) {
          const float* s2 = srcA + (ck + 1) * 128;
#pragma unroll
          for (int ks = 0; ks < 4; ++ks) {
            ra[2 * ks]     = *(const float4*)(s2 + ks * 32);
            ra[2 * ks + 1] = *(const float4*)(s2 + ks * 32 + 4);
          }
        } else {
#pragma unroll
          for (int c = 0; c < 4; ++c) {
            const int m0 = (ck + 1) * 128 + wv4 * 32 + c * 8;
#pragma unroll
            for (int j = 0; j < 8; ++j) wreg[c * 8 + j] = W[(size_t)(m0 + j) * 512 + d];
          }
        }
      }
#pragma unroll
      for (int t3 = kh * 2; t3 < kh * 2 + 2; ++t3)
        mfma_tiles(As + t3 * 2048, Bs + t3 * 2048, wr, wc, lane, acc);
      __syncthreads();
    }
    if (kh) {
#pragma unroll
      for (int mi = 0; mi < 2; ++mi)
#pragma unroll
        for (int ni = 0; ni < 2; ++ni)
#pragma unroll
          for (int jx = 0; jx < 4; ++jx)
            accx[q][lane][(mi * 2 + ni) * 4 + jx] = acc[mi][ni][jx];
    }
    __syncthreads();
    if (kh) return;
#pragma unroll
    for (int mi = 0; mi < 2; ++mi)
#pragma unroll
      for (int ni = 0; ni < 2; ++ni)
#pragma unroll
        for (int jx = 0; jx < 4; ++jx)
          acc[mi][ni][jx] += accx[q][lane][(mi * 2 + ni) * 4 + jx];
#pragma unroll
    for (int mi = 0; mi < 2; ++mi)
#pragma unroll
      for (int ni = 0; ni < 2; ++ni) {
        const int c = bn + (wc << 5) + (ni << 4) + (lane & 15);
        const int rb2 = bm + (wr << 5) + (mi << 4) + ((lane >> 4) << 2);
        if (TP[job] >= 0) {
          bf16x4 pk;
#pragma unroll
          for (int jx = 0; jx < 4; ++jx) pk[jx] = f2bf(acc[mi][ni][jx]);
          short* PW = SH + SB_PW + TP[job] * 131072 + (c >> 6) * 16384;
          const int idx = (rb2 >> 5) * 2048 + (((c & 63) >> 4) << 9) + (((rb2 & 31) >> 3) << 7)
                        + ((c & 15) << 3) + (rb2 & 7);
          *(bf16x4*)(PW + idx) = pk;
        }
        if (F32[job] >= 0) {
          float* TW = ws + WF_TW + F32[job] * 131072;
#pragma unroll
          for (int jx = 0; jx < 4; ++jx)
            TW[(size_t)(rb2 + jx) * DN + c] = acc[mi][ni][jx];
        }
      }
  }
}

// ---- S23: c@XW + (own g-strip -> h) @ PW, tanh, atomic main ----
__global__ __launch_bounds__(512) void s23_k(Pk p) {
  float* ws = p.ws;
  short* SH = (short*)(ws + WF_BF);
  __shared__ __align__(16) short Cs[16384];
  __shared__ float accg[4][64][16];
  __shared__ float srs_lds[256], E_lds[256], d0_lds[64];
  // XCD-aware bijective swizzle: 96 = 8 * 12
  const int bid = ((blockIdx.x & 7) * 12) + (blockIdx.x >> 3);
  const int tid = threadIdx.x;
  const int lane = tid & 63, w = tid >> 6;
  const int q = w & 3, kf = w >> 2;
  const int wr = q >> 1, wc = q & 1;
  const int job = bid >> 5, t = bid & 31;
  const int bm = (t >> 3) << 6, bn = (t & 7) << 6;

  const int SRC[3] = {0, 2, 4};
  const int SRS[3] = {0, 1, 3};
  const int D0M[3] = {0, 2, 4};
  const int PWH[3] = {0, 2, 0};
  const int PWC[3] = {1, 3, 4};

  // issue c-strip loads first (independent of partials)
  const int r = tid >> 3, s8 = tid & 7;
  const int qq = s8 & 3, ih = s8 >> 2;
  const float* srcc = ws + WF_S + SRC[job] * 65536 + (size_t)(bm + r) * 256;
  float xr[32];
#pragma unroll
  for (int i = 0; i < 4; ++i) {
    const int k0 = (i * 2 + ih) * 32 + (qq << 3);
    *(float4*)&xr[i * 8]     = *(const float4*)(srcc + k0);
    *(float4*)&xr[i * 8 + 4] = *(const float4*)(srcc + k0 + 4);
  }

  if (tid < 256) {
    const float* rp = ws + WF_RP + SRS[job] * 2048;
    float s = 1.f;
#pragma unroll
    for (int tc = 0; tc < 8; ++tc) s += rp[tc * 256 + tid];
    srs_lds[tid] = s;
  } else if (job < 2) {
    const float* ec = ws + WF_EC + job * 2048;
    float s = 0.f;
#pragma unroll
    for (int tr = 0; tr < 8; ++tr) s += ec[tr * 256 + (tid - 256)];
    E_lds[tid - 256] = s;
  }
  if (tid < 64) {
    const float* rp = ws + WF_RP + D0M[job] * 2048;
    float s = 2.f;
#pragma unroll
    for (int tc = 0; tc < 8; ++tc) s += rp[tc * 256 + bm + tid];
    d0_lds[tid] = rsqrtf(s);
  }
  __syncthreads();

  {  // transform + store c strip
#pragma unroll
    for (int i = 0; i < 4; ++i) {
      const int ti = i * 2 + ih;
      const int k0 = ti * 32 + (qq << 3);
      bf16x8 pk;
#pragma unroll
      for (int j = 0; j < 8; ++j) {
        const float rv = fmaxf(xr[i * 8 + j], 0.f);
        pk[j] = f2bf(rv * rsqrtf(srs_lds[k0 + j] + rv));
      }
      *(bf16x8*)&Cs[ti * 2048 + ((r >> 4) << 9) + (qq << 7) + ((r & 15) << 3)] = pk;
    }
  }
  __syncthreads();

  // prefetch e0 for h epilogue (job<2), hidden under the GEMMs below
  float er[4][2][4];
  if (job < 2) {
    const float* e0 = ws + WF_E + (job ? 2 : 0) * 65536;
#pragma unroll
    for (int mi = 0; mi < 4; ++mi)
#pragma unroll
      for (int nj = 0; nj < 2; ++nj) {
        const int col = (w << 5) + (nj << 4) + (lane & 15);
#pragma unroll
        for (int jx = 0; jx < 4; ++jx) {
          const int row = (mi << 4) + ((lane >> 4) << 2) + jx;
          er[mi][nj][jx] = e0[(size_t)(bm + row) * 256 + col];
        }
      }
  }

  // c @ XW  (quadrant q, K-half kf)
  f32x4 acc2[2][2] = {};
  const short* PWcb = SH + SB_PW + PWC[job] * 131072 + (bn >> 6) * 16384;
#pragma unroll
  for (int i = kf * 4; i < kf * 4 + 4; ++i)
    mfma_tiles(Cs + i * 2048, PWcb + i * 2048, wr, wc, lane, acc2);

  if (job < 2) {
    // own g strip: wave w computes g[64][w*32 .. w*32+32] over full K=256
    f32x4 acc16[4][2] = {};
    const short* EB = SH + SB_ETP + job * 65536 + (w >> 1) * 16384;
    const int bh = (w & 1) << 1;
#pragma unroll
    for (int i2 = 0; i2 < 8; ++i2) {
      const short* at = Cs + i2 * 2048;
      const short* bt = EB + i2 * 2048;
      const bf16x8 fb0 = *(const bf16x8*)(bt + ((bh + 0) << 9) + (lane << 3));
      const bf16x8 fb1 = *(const bf16x8*)(bt + ((bh + 1) << 9) + (lane << 3));
#pragma unroll
      for (int mi = 0; mi < 4; ++mi) {
        const bf16x8 fa = *(const bf16x8*)(at + (mi << 9) + (lane << 3));
        acc16[mi][0] = __builtin_amdgcn_mfma_f32_16x16x32_bf16(fa, fb0, acc16[mi][0], 0, 0, 0);
        acc16[mi][1] = __builtin_amdgcn_mfma_f32_16x16x32_bf16(fa, fb1, acc16[mi][1], 0, 0, 0);
      }
    }
    __syncthreads();
    short* Ht = Cs + w * 2048;
#pragma unroll
    for (int mi = 0; mi < 4; ++mi)
#pragma unroll
      for (int nj = 0; nj < 2; ++nj) {
        const int kc = (nj << 4) + (lane & 15);
        const int col = (w << 5) + kc;
#pragma unroll
        for (int jx = 0; jx < 4; ++jx) {
          const int row = (mi << 4) + ((lane >> 4) << 2) + jx;
          const float e = er[mi][nj][jx];
          const float hv = (2.f * d0_lds[row] * e + acc16[mi][nj][jx]) / (e + E_lds[col]);
          Ht[((row >> 4) << 9) + ((kc >> 3) << 7) + ((row & 15) << 3) + (kc & 7)] = f2bf(hv);
        }
      }
    __syncthreads();
    const short* PWhb = SH + SB_PW + PWH[job] * 131072 + (bn >> 6) * 16384;
#pragma unroll
    for (int i = kf * 4; i < kf * 4 + 4; ++i)
      mfma_tiles(Cs + i * 2048, PWhb + i * 2048, wr, wc, lane, acc2);
  }

  if (kf) {
#pragma unroll
    for (int mi = 0; mi < 2; ++mi)
#pragma unroll
      for (int ni = 0; ni < 2; ++ni)
#pragma unroll
        for (int jx = 0; jx < 4; ++jx)
          accg[q][lane][(mi * 2 + ni) * 4 + jx] = acc2[mi][ni][jx];
  }
  __syncthreads();
  if (kf) return;
#pragma unroll
  for (int mi = 0; mi < 2; ++mi)
#pragma unroll
    for (int ni = 0; ni < 2; ++ni)
#pragma unroll
      for (int jx = 0; jx < 4; ++jx)
        acc2[mi][ni][jx] += accg[q][lane][(mi * 2 + ni) * 4 + jx];

  const float* TW = ws + WF_TW + job * 131072;
  const float* bias = (job == 0) ? p.b_tt : (job == 1) ? p.b_it : p.b_ntt;
  float* O = p.out + (size_t)(job + 1) * CN * DN;
  const float coef = (job == 0) ? 0.35f : 0.15f;
#pragma unroll
  for (int mi = 0; mi < 2; ++mi)
#pragma unroll
    for (int ni = 0; ni < 2; ++ni) {
      const int cl = (wc << 5) + (ni << 4) + (lane & 15);
      const int rb = (wr << 5) + (mi << 4) + ((lane >> 4) << 2);
#pragma unroll
      for (int jx = 0; jx < 4; ++jx) {
        const int rl = rb + jx;
        const size_t idx = (size_t)(bm + rl) * DN + bn + cl;
        const float d = d0_lds[rl];
        const float o = tanhf(d * (acc2[mi][ni][jx] + 2.f * d * TW[idx]) + bias[idx]);
        O[idx] = o;
        if (job < 2) atomicAdd(p.out + idx, coef * o);
      }
    }
}

extern "C" void kernel_launch(void* const* d_in, const int* in_sizes, int n_in,
                              void* d_out, int out_size, void* d_ws, size_t ws_size,
                              hipStream_t stream) {
  Pk prm;
  prm.img_feature = (const float*)d_in[0];
  prm.text  = (const float*)d_in[1];
  prm.img   = (const float*)d_in[2];
  prm.neg   = (const float*)d_in[3];
  prm.p_t   = (const float*)d_in[4];
  prm.aw_t  = (const float*)d_in[5];
  prm.ab_t  = (const float*)d_in[6];
  prm.p_i   = (const float*)d_in[7];
  prm.aw_i  = (const float*)d_in[8];
  prm.ab_i  = (const float*)d_in[9];
  prm.W_tt  = (const float*)d_in[10];
  prm.b_tt  = (const float*)d_in[11];
  prm.W_it  = (const float*)d_in[12];
  prm.b_it  = (const float*)d_in[13];
  prm.W_ntt = (const float*)d_in[14];
  prm.b_ntt = (const float*)d_in[15];
  prm.out = (float*)d_out;
  prm.ws  = (float*)d_ws;

  s1_k<<<352, 512, 0, stream>>>(prm);
  s23_k<<<96, 512, 0, stream>>>(prm);
}

// Round 14
// 39.336 us; speedup vs baseline: 1.1287x; 1.1287x over previous
//
#include <hip/hip_runtime.h>
#include <math.h>

#define CN 256
#define DN 512

typedef __attribute__((ext_vector_type(8))) short bf16x8;
typedef __attribute__((ext_vector_type(4))) short bf16x4;
typedef __attribute__((ext_vector_type(4))) float f32x4;

__device__ __forceinline__ short f2bf(float f) {
  unsigned u = __float_as_uint(f);
  u += 0x7fffu + ((u >> 16) & 1u);
  return (short)(u >> 16);
}

__device__ __forceinline__ bf16x8 pack8(float4 a, float4 b) {
  bf16x8 r;
  r[0] = f2bf(a.x); r[1] = f2bf(a.y); r[2] = f2bf(a.z); r[3] = f2bf(a.w);
  r[4] = f2bf(b.x); r[5] = f2bf(b.y); r[6] = f2bf(b.z); r[7] = f2bf(b.w);
  return r;
}

__device__ __forceinline__ float d4(float4 v) {
  return v.x * v.x + v.y * v.y + v.z * v.z + v.w * v.w;
}

struct Pk {
  const float *img_feature, *text, *img, *neg;
  const float *p_t, *aw_t, *ab_t, *p_i, *aw_i, *ab_i;
  const float *W_tt, *b_tt, *W_it, *b_it, *W_ntt, *b_ntt;
  float* out; float* ws;
};

// ---- f32 workspace (float offsets) ----
#define WF_S   0
#define WF_E   327680
#define WF_RP  524288
#define WF_EC  534528
#define WF_TW  540672
#define WF_BF  933888

// ---- bf16 panel region (short offsets) ----
#define SB_ETP   1703936
#define SB_PW    1966080

__device__ __forceinline__ void mfma_tiles(const short* at, const short* bt,
                                           int wr, int wc, int lane, f32x4 (&acc)[2][2]) {
  const bf16x8 fa0 = *(const bf16x8*)(at + ((wr << 1) << 9) + (lane << 3));
  const bf16x8 fa1 = *(const bf16x8*)(at + (((wr << 1) + 1) << 9) + (lane << 3));
  const bf16x8 fb0 = *(const bf16x8*)(bt + ((wc << 1) << 9) + (lane << 3));
  const bf16x8 fb1 = *(const bf16x8*)(bt + (((wc << 1) + 1) << 9) + (lane << 3));
  acc[0][0] = __builtin_amdgcn_mfma_f32_16x16x32_bf16(fa0, fb0, acc[0][0], 0, 0, 0);
  acc[0][1] = __builtin_amdgcn_mfma_f32_16x16x32_bf16(fa0, fb1, acc[0][1], 0, 0, 0);
  acc[1][0] = __builtin_amdgcn_mfma_f32_16x16x32_bf16(fa1, fb0, acc[1][0], 0, 0, 0);
  acc[1][1] = __builtin_amdgcn_mfma_f32_16x16x32_bf16(fa1, fb1, acc[1][1], 0, 0, 0);
}

// ---- S1: 8 NT GEMMs + 7 pre-GEMMs, register-prefetch pipelined staging ----
__global__ __launch_bounds__(512) void s1_k(Pk p) {
  float* ws = p.ws;
  short* SH = (short*)(ws + WF_BF);
  __shared__ __align__(16) short As[8192];
  __shared__ __align__(16) short Bs[8192];
  __shared__ float accx[4][64][16];
  __shared__ float invA_lds[64], invB_lds[64];
  const int bid = blockIdx.x;   // no XCD swizzle: heterogeneous job types make
                                // per-XCD chunks unbalanced (round-13 regression)
  const int tid = threadIdx.x;
  const int lane = tid & 63, w = tid >> 6;
  const int q = w & 3, kh = w >> 2;
  const int wr = q >> 1, wc = q & 1;
  const int sr = (tid & 255) >> 2, sq = tid & 3;

  const float* XL[7] = {p.text, p.img, p.neg, p.aw_t, p.aw_i, p.p_t, p.p_i};

  if (bid < 128) {
    const int job = bid >> 4, tile = bid & 15;
    const int bm = (tile >> 2) << 6, bn = (tile & 3) << 6;

    const int AM[8] = {0, 1, 0, 2, 0, 0, 1, 0};
    const int BM[8] = {0, 1, 1, 2, 2, 3, 4, 4};
    const float* A = XL[AM[job]];
    const float* B = XL[BM[job]];
    const float* srcT = (tid < 256 ? A + (size_t)(bm + sr) * 512
                                   : B + (size_t)(bn + sr) * 512) + (sq << 3);
    short* dst = (tid < 256) ? As : Bs;
    f32x4 acc[2][2] = {};
    float ss = 0.f;
    float4 r0[8];
#pragma unroll
    for (int ks = 0; ks < 4; ++ks) {
      r0[2 * ks]     = *(const float4*)(srcT + ks * 32);
      r0[2 * ks + 1] = *(const float4*)(srcT + ks * 32 + 4);
    }
    // out-init / passthrough issued AFTER chunk-0 loads (latency overlap)
    if (tid < 256) p.out[4 * CN * DN + bid * 256 + tid] = p.img_feature[bid * 256 + tid];
    {
      const int i0 = bid * 1024 + tid;
      p.out[i0] = 0.5f * p.text[i0];
      p.out[i0 + 512] = 0.5f * p.text[i0 + 512];
    }
    for (int ck = 0; ck < 4; ++ck) {
#pragma unroll
      for (int ks = 0; ks < 4; ++ks) {
        ss += d4(r0[2 * ks]) + d4(r0[2 * ks + 1]);
        *(bf16x8*)&dst[ks * 2048 + ((sr >> 4) << 9) + (sq << 7) + ((sr & 15) << 3)]
            = pack8(r0[2 * ks], r0[2 * ks + 1]);
      }
      __syncthreads();
      if (ck < 3) {
        const float* s2 = srcT + (ck + 1) * 128;
#pragma unroll
        for (int ks = 0; ks < 4; ++ks) {
          r0[2 * ks]     = *(const float4*)(s2 + ks * 32);
          r0[2 * ks + 1] = *(const float4*)(s2 + ks * 32 + 4);
        }
      }
#pragma unroll
      for (int t3 = kh * 2; t3 < kh * 2 + 2; ++t3)
        mfma_tiles(As + t3 * 2048, Bs + t3 * 2048, wr, wc, lane, acc);
      __syncthreads();
    }

    if (job < 5) {
      ss += __shfl_xor(ss, 1, 64);
      ss += __shfl_xor(ss, 2, 64);
      if (sq == 0) {
        const float iv = 1.f / fmaxf(sqrtf(ss), 1e-12f);
        if (tid < 256) invA_lds[sr] = iv;
        else           invB_lds[sr] = iv;
      }
    }
    if (kh) {
#pragma unroll
      for (int mi = 0; mi < 2; ++mi)
#pragma unroll
        for (int ni = 0; ni < 2; ++ni)
#pragma unroll
          for (int jx = 0; jx < 4; ++jx)
            accx[q][lane][(mi * 2 + ni) * 4 + jx] = acc[mi][ni][jx];
    }
    __syncthreads();
    if (kh) return;
#pragma unroll
    for (int mi = 0; mi < 2; ++mi)
#pragma unroll
      for (int ni = 0; ni < 2; ++ni)
#pragma unroll
        for (int jx = 0; jx < 4; ++jx)
          acc[mi][ni][jx] += accx[q][lane][(mi * 2 + ni) * 4 + jx];

    float sv[2][2][4];
    if (job < 5) {
      float* C = ws + WF_S + job * 65536;
#pragma unroll
      for (int mi = 0; mi < 2; ++mi)
#pragma unroll
        for (int ni = 0; ni < 2; ++ni) {
          const int cl = (wc << 5) + (ni << 4) + (lane & 15);
#pragma unroll
          for (int jx = 0; jx < 4; ++jx) {
            const int rl = (wr << 5) + (mi << 4) + ((lane >> 4) << 2) + jx;
            const float v = acc[mi][ni][jx] * invA_lds[rl] * invB_lds[cl];
            sv[mi][ni][jx] = v;
            C[(size_t)(bm + rl) * CN + bn + cl] = v;
          }
        }
      float* rp = ws + WF_RP + job * 2048 + ((bn >> 5) + wc) * 256;
#pragma unroll
      for (int mi = 0; mi < 2; ++mi)
#pragma unroll
        for (int jx = 0; jx < 4; ++jx) {
          float s = fmaxf(sv[mi][0][jx], 0.f) + fmaxf(sv[mi][1][jx], 0.f);
          s += __shfl_xor(s, 1, 64); s += __shfl_xor(s, 2, 64);
          s += __shfl_xor(s, 4, 64); s += __shfl_xor(s, 8, 64);
          if ((lane & 15) == 0) {
            const int rl = (wr << 5) + (mi << 4) + ((lane >> 4) << 2) + jx;
            rp[bm + rl] = s;
          }
        }
    } else {
      const int z = job - 5;
      const float* bias = (job == 5) ? p.ab_t : p.ab_i;
      float* C = ws + WF_E + z * 65536;
#pragma unroll
      for (int mi = 0; mi < 2; ++mi)
#pragma unroll
        for (int ni = 0; ni < 2; ++ni) {
          const int cl = (wc << 5) + (ni << 4) + (lane & 15);
          const int rb2 = (wr << 5) + (mi << 4) + ((lane >> 4) << 2);
#pragma unroll
          for (int jx = 0; jx < 4; ++jx) {
            const float v = expf(acc[mi][ni][jx] + bias[bn + cl]);
            sv[mi][ni][jx] = v;
            C[(size_t)(bm + rb2 + jx) * CN + bn + cl] = v;
          }
          if (z < 2) {
            bf16x4 pk;
#pragma unroll
            for (int jx = 0; jx < 4; ++jx) pk[jx] = f2bf(sv[mi][ni][jx]);
            short* ET = SH + SB_ETP + z * 65536 + (bn >> 6) * 16384 + (bm >> 5) * 2048;
            const int idx = (rb2 >> 5) * 2048 + ((cl >> 4) << 9) + (((rb2 & 31) >> 3) << 7)
                          + ((cl & 15) << 3) + (rb2 & 7);
            *(bf16x4*)(ET + idx) = pk;
          }
        }
      if (z < 2) {
        float* ec = ws + WF_EC + z * 2048 + ((bm >> 5) + wr) * 256;
#pragma unroll
        for (int ni = 0; ni < 2; ++ni) {
          float s = 0.f;
#pragma unroll
          for (int mi = 0; mi < 2; ++mi)
#pragma unroll
            for (int jx = 0; jx < 4; ++jx) s += sv[mi][ni][jx];
          s += __shfl_xor(s, 16, 64); s += __shfl_xor(s, 32, 64);
          if ((lane >> 4) == 0) ec[bn + (wc << 5) + (ni << 4) + (lane & 15)] = s;
        }
      }
    }
  } else {
    // pre-GEMMs: X@W, 64x64 tiles, pipelined
    const int t2 = bid - 128, job = t2 >> 5, tile = t2 & 31;
    const int bm = (tile >> 3) << 6, bn = (tile & 7) << 6;
    const int AJ[7] = {5, 0, 6, 1, 0, 2, 0};
    const int WJ[7] = {0, 0, 1, 1, 1, 2, 2};
    const int TP[7] = {0, 1, 2, 3, -1, 4, -1};
    const int F32[7] = {-1, 0, -1, -1, 1, -1, 2};
    const float* A = XL[AJ[job]];
    const float* W = (WJ[job] == 0) ? p.W_tt : (WJ[job] == 1) ? p.W_it : p.W_ntt;
    const int wv4 = w & 3;
    const int d = bn + lane;
    f32x4 acc[2][2] = {};
    const float* srcA = A + (size_t)(bm + sr) * 512 + (sq << 3);
    float4 ra[8];
    float wreg[32];
    if (tid < 256) {
#pragma unroll
      for (int ks = 0; ks < 4; ++ks) {
        ra[2 * ks]     = *(const float4*)(srcA + ks * 32);
        ra[2 * ks + 1] = *(const float4*)(srcA + ks * 32 + 4);
      }
    } else {
#pragma unroll
      for (int c = 0; c < 4; ++c) {
        const int m0 = wv4 * 32 + c * 8;
#pragma unroll
        for (int j = 0; j < 8; ++j) wreg[c * 8 + j] = W[(size_t)(m0 + j) * 512 + d];
      }
    }
    for (int ck = 0; ck < 4; ++ck) {
      if (tid < 256) {
#pragma unroll
        for (int ks = 0; ks < 4; ++ks)
          *(bf16x8*)&As[ks * 2048 + ((sr >> 4) << 9) + (sq << 7) + ((sr & 15) << 3)]
              = pack8(ra[2 * ks], ra[2 * ks + 1]);
      } else {
#pragma unroll
        for (int c = 0; c < 4; ++c) {
          bf16x8 pk;
#pragma unroll
          for (int j = 0; j < 8; ++j) pk[j] = f2bf(wreg[c * 8 + j]);
          *(bf16x8*)&Bs[wv4 * 2048 + ((lane >> 4) << 9) + (c << 7) + ((lane & 15) << 3)] = pk;
        }
      }
      __syncthreads();
      if (ck < 3) {
        if (tid < 256) {
          const float* s2 = srcA + (ck + 1) * 128;
#pragma unroll
          for (int ks = 0; ks < 4; ++ks) {
            ra[2 * ks]     = *(const float4*)(s2 + ks * 32);
            ra[2 * ks + 1] = *(const float4*)(s2 + ks * 32 + 4);
          }
        } else {
#pragma unroll
          for (int c = 0; c < 4; ++c) {
            const int m0 = (ck + 1) * 128 + wv4 * 32 + c * 8;
#pragma unroll
            for (int j = 0; j < 8; ++j) wreg[c * 8 + j] = W[(size_t)(m0 + j) * 512 + d];
          }
        }
      }
#pragma unroll
      for (int t3 = kh * 2; t3 < kh * 2 + 2; ++t3)
        mfma_tiles(As + t3 * 2048, Bs + t3 * 2048, wr, wc, lane, acc);
      __syncthreads();
    }
    if (kh) {
#pragma unroll
      for (int mi = 0; mi < 2; ++mi)
#pragma unroll
        for (int ni = 0; ni < 2; ++ni)
#pragma unroll
          for (int jx = 0; jx < 4; ++jx)
            accx[q][lane][(mi * 2 + ni) * 4 + jx] = acc[mi][ni][jx];
    }
    __syncthreads();
    if (kh) return;
#pragma unroll
    for (int mi = 0; mi < 2; ++mi)
#pragma unroll
      for (int ni = 0; ni < 2; ++ni)
#pragma unroll
        for (int jx = 0; jx < 4; ++jx)
          acc[mi][ni][jx] += accx[q][lane][(mi * 2 + ni) * 4 + jx];
#pragma unroll
    for (int mi = 0; mi < 2; ++mi)
#pragma unroll
      for (int ni = 0; ni < 2; ++ni) {
        const int c = bn + (wc << 5) + (ni << 4) + (lane & 15);
        const int rb2 = bm + (wr << 5) + (mi << 4) + ((lane >> 4) << 2);
        if (TP[job] >= 0) {
          bf16x4 pk;
#pragma unroll
          for (int jx = 0; jx < 4; ++jx) pk[jx] = f2bf(acc[mi][ni][jx]);
          short* PW = SH + SB_PW + TP[job] * 131072 + (c >> 6) * 16384;
          const int idx = (rb2 >> 5) * 2048 + (((c & 63) >> 4) << 9) + (((rb2 & 31) >> 3) << 7)
                        + ((c & 15) << 3) + (rb2 & 7);
          *(bf16x4*)(PW + idx) = pk;
        }
        if (F32[job] >= 0) {
          float* TW = ws + WF_TW + F32[job] * 131072;
#pragma unroll
          for (int jx = 0; jx < 4; ++jx)
            TW[(size_t)(rb2 + jx) * DN + c] = acc[mi][ni][jx];
        }
      }
  }
}

// ---- S23: c@XW + (own g-strip -> h) @ PW, tanh, atomic main ----
__global__ __launch_bounds__(512) void s23_k(Pk p) {
  float* ws = p.ws;
  short* SH = (short*)(ws + WF_BF);
  __shared__ __align__(16) short Cs[16384];
  __shared__ float accg[4][64][16];
  __shared__ float srs_lds[256], E_lds[256], d0_lds[64];
  const int bid = blockIdx.x;
  const int tid = threadIdx.x;
  const int lane = tid & 63, w = tid >> 6;
  const int q = w & 3, kf = w >> 2;
  const int wr = q >> 1, wc = q & 1;
  const int job = bid >> 5, t = bid & 31;
  const int bm = (t >> 3) << 6, bn = (t & 7) << 6;

  const int SRC[3] = {0, 2, 4};
  const int SRS[3] = {0, 1, 3};
  const int D0M[3] = {0, 2, 4};
  const int PWH[3] = {0, 2, 0};
  const int PWC[3] = {1, 3, 4};

  // issue c-strip loads first (independent of partials)
  const int r = tid >> 3, s8 = tid & 7;
  const int qq = s8 & 3, ih = s8 >> 2;
  const float* srcc = ws + WF_S + SRC[job] * 65536 + (size_t)(bm + r) * 256;
  float xr[32];
#pragma unroll
  for (int i = 0; i < 4; ++i) {
    const int k0 = (i * 2 + ih) * 32 + (qq << 3);
    *(float4*)&xr[i * 8]     = *(const float4*)(srcc + k0);
    *(float4*)&xr[i * 8 + 4] = *(const float4*)(srcc + k0 + 4);
  }

  if (tid < 256) {
    const float* rp = ws + WF_RP + SRS[job] * 2048;
    float s = 1.f;
#pragma unroll
    for (int tc = 0; tc < 8; ++tc) s += rp[tc * 256 + tid];
    srs_lds[tid] = s;
  } else if (job < 2) {
    const float* ec = ws + WF_EC + job * 2048;
    float s = 0.f;
#pragma unroll
    for (int tr = 0; tr < 8; ++tr) s += ec[tr * 256 + (tid - 256)];
    E_lds[tid - 256] = s;
  }
  if (tid < 64) {
    const float* rp = ws + WF_RP + D0M[job] * 2048;
    float s = 2.f;
#pragma unroll
    for (int tc = 0; tc < 8; ++tc) s += rp[tc * 256 + bm + tid];
    d0_lds[tid] = rsqrtf(s);
  }
  __syncthreads();

  {  // transform + store c strip
#pragma unroll
    for (int i = 0; i < 4; ++i) {
      const int ti = i * 2 + ih;
      const int k0 = ti * 32 + (qq << 3);
      bf16x8 pk;
#pragma unroll
      for (int j = 0; j < 8; ++j) {
        const float rv = fmaxf(xr[i * 8 + j], 0.f);
        pk[j] = f2bf(rv * rsqrtf(srs_lds[k0 + j] + rv));
      }
      *(bf16x8*)&Cs[ti * 2048 + ((r >> 4) << 9) + (qq << 7) + ((r & 15) << 3)] = pk;
    }
  }
  __syncthreads();

  // prefetch e0 for h epilogue (job<2), hidden under the GEMMs below
  float er[4][2][4];
  if (job < 2) {
    const float* e0 = ws + WF_E + (job ? 2 : 0) * 65536;
#pragma unroll
    for (int mi = 0; mi < 4; ++mi)
#pragma unroll
      for (int nj = 0; nj < 2; ++nj) {
        const int col = (w << 5) + (nj << 4) + (lane & 15);
#pragma unroll
        for (int jx = 0; jx < 4; ++jx) {
          const int row = (mi << 4) + ((lane >> 4) << 2) + jx;
          er[mi][nj][jx] = e0[(size_t)(bm + row) * 256 + col];
        }
      }
  }

  // c @ XW  (quadrant q, K-half kf)
  f32x4 acc2[2][2] = {};
  const short* PWcb = SH + SB_PW + PWC[job] * 131072 + (bn >> 6) * 16384;
#pragma unroll
  for (int i = kf * 4; i < kf * 4 + 4; ++i)
    mfma_tiles(Cs + i * 2048, PWcb + i * 2048, wr, wc, lane, acc2);

  if (job < 2) {
    // own g strip: wave w computes g[64][w*32 .. w*32+32] over full K=256
    f32x4 acc16[4][2] = {};
    const short* EB = SH + SB_ETP + job * 65536 + (w >> 1) * 16384;
    const int bh = (w & 1) << 1;
#pragma unroll
    for (int i2 = 0; i2 < 8; ++i2) {
      const short* at = Cs + i2 * 2048;
      const short* bt = EB + i2 * 2048;
      const bf16x8 fb0 = *(const bf16x8*)(bt + ((bh + 0) << 9) + (lane << 3));
      const bf16x8 fb1 = *(const bf16x8*)(bt + ((bh + 1) << 9) + (lane << 3));
#pragma unroll
      for (int mi = 0; mi < 4; ++mi) {
        const bf16x8 fa = *(const bf16x8*)(at + (mi << 9) + (lane << 3));
        acc16[mi][0] = __builtin_amdgcn_mfma_f32_16x16x32_bf16(fa, fb0, acc16[mi][0], 0, 0, 0);
        acc16[mi][1] = __builtin_amdgcn_mfma_f32_16x16x32_bf16(fa, fb1, acc16[mi][1], 0, 0, 0);
      }
    }
    __syncthreads();
    short* Ht = Cs + w * 2048;
#pragma unroll
    for (int mi = 0; mi < 4; ++mi)
#pragma unroll
      for (int nj = 0; nj < 2; ++nj) {
        const int kc = (nj << 4) + (lane & 15);
        const int col = (w << 5) + kc;
#pragma unroll
        for (int jx = 0; jx < 4; ++jx) {
          const int row = (mi << 4) + ((lane >> 4) << 2) + jx;
          const float e = er[mi][nj][jx];
          const float hv = (2.f * d0_lds[row] * e + acc16[mi][nj][jx]) / (e + E_lds[col]);
          Ht[((row >> 4) << 9) + ((kc >> 3) << 7) + ((row & 15) << 3) + (kc & 7)] = f2bf(hv);
        }
      }
    __syncthreads();
    const short* PWhb = SH + SB_PW + PWH[job] * 131072 + (bn >> 6) * 16384;
#pragma unroll
    for (int i = kf * 4; i < kf * 4 + 4; ++i)
      mfma_tiles(Cs + i * 2048, PWhb + i * 2048, wr, wc, lane, acc2);
  }

  if (kf) {
#pragma unroll
    for (int mi = 0; mi < 2; ++mi)
#pragma unroll
      for (int ni = 0; ni < 2; ++ni)
#pragma unroll
        for (int jx = 0; jx < 4; ++jx)
          accg[q][lane][(mi * 2 + ni) * 4 + jx] = acc2[mi][ni][jx];
  }
  __syncthreads();
  if (kf) return;
#pragma unroll
  for (int mi = 0; mi < 2; ++mi)
#pragma unroll
    for (int ni = 0; ni < 2; ++ni)
#pragma unroll
      for (int jx = 0; jx < 4; ++jx)
        acc2[mi][ni][jx] += accg[q][lane][(mi * 2 + ni) * 4 + jx];

  const float* TW = ws + WF_TW + job * 131072;
  const float* bias = (job == 0) ? p.b_tt : (job == 1) ? p.b_it : p.b_ntt;
  float* O = p.out + (size_t)(job + 1) * CN * DN;
  const float coef = (job == 0) ? 0.35f : 0.15f;
#pragma unroll
  for (int mi = 0; mi < 2; ++mi)
#pragma unroll
    for (int ni = 0; ni < 2; ++ni) {
      const int cl = (wc << 5) + (ni << 4) + (lane & 15);
      const int rb = (wr << 5) + (mi << 4) + ((lane >> 4) << 2);
#pragma unroll
      for (int jx = 0; jx < 4; ++jx) {
        const int rl = rb + jx;
        const size_t idx = (size_t)(bm + rl) * DN + bn + cl;
        const float d = d0_lds[rl];
        const float o = tanhf(d * (acc2[mi][ni][jx] + 2.f * d * TW[idx]) + bias[idx]);
        O[idx] = o;
        if (job < 2) atomicAdd(p.out + idx, coef * o);
      }
    }
}

extern "C" void kernel_launch(void* const* d_in, const int* in_sizes, int n_in,
                              void* d_out, int out_size, void* d_ws, size_t ws_size,
                              hipStream_t stream) {
  Pk prm;
  prm.img_feature = (const float*)d_in[0];
  prm.text  = (const float*)d_in[1];
  prm.img   = (const float*)d_in[2];
  prm.neg   = (const float*)d_in[3];
  prm.p_t   = (const float*)d_in[4];
  prm.aw_t  = (const float*)d_in[5];
  prm.ab_t  = (const float*)d_in[6];
  prm.p_i   = (const float*)d_in[7];
  prm.aw_i  = (const float*)d_in[8];
  prm.ab_i  = (const float*)d_in[9];
  prm.W_tt  = (const float*)d_in[10];
  prm.b_tt  = (const float*)d_in[11];
  prm.W_it  = (const float*)d_in[12];
  prm.b_it  = (const float*)d_in[13];
  prm.W_ntt = (const float*)d_in[14];
  prm.b_ntt = (const float*)d_in[15];
  prm.out = (float*)d_out;
  prm.ws  = (float*)d_ws;

  s1_k<<<352, 512, 0, stream>>>(prm);
  s23_k<<<96, 512, 0, stream>>>(prm);
}